// Round 14
// baseline (523.368 us; speedup 1.0000x reference)
//
#include <hip/hip_runtime.h>
#include <hip/hip_bf16.h>
#include <math.h>

#define H 1024
#define F 3584
#define F2 7168
#define NE 8
#define T 1024

typedef __attribute__((ext_vector_type(4))) float f32x4;
typedef __attribute__((ext_vector_type(8))) short bf16x8;
typedef __attribute__((ext_vector_type(4))) unsigned u32x4;

__device__ inline short f2bf(float f) {
  union { float f; unsigned u; } v; v.f = f;
  unsigned r = (v.u + 0x7FFFu + ((v.u >> 16) & 1u)) >> 16;
  return (short)r;
}

__device__ inline unsigned pkbf(float a, float b) {
  unsigned r;
  asm("v_cvt_pk_bf16_f32 %0, %1, %2" : "=v"(r) : "v"(a), "v"(b));
  return r;
}

#define MFMA16(af, bf, c) __builtin_amdgcn_mfma_f32_16x16x32_bf16((af), (bf), (c), 0, 0, 0)

// ---------------- weight transpose+convert: in [K][C] fp32 -> out [C][K] bf16 ----------------
// 64x64 tiles via LDS. HBM-bound by design (528 MB total traffic).
__global__ __launch_bounds__(256) void tr_k(
    const float* __restrict__ in, unsigned short* __restrict__ outp, int K, int C)
{
  int e = blockIdx.z;
  int ct = blockIdx.x * 64;
  int kt = blockIdx.y * 64;
  const float* ib = in + (size_t)e * K * C + (size_t)kt * C + ct;
  unsigned short* ob = outp + (size_t)e * C * K + (size_t)ct * K + kt;

  __shared__ unsigned short tile[64][66];
  int t = threadIdx.x;
  int tc = (t & 15) * 4;
  int tk = t >> 4;
  #pragma unroll
  for (int i = 0; i < 4; ++i) {
    int k = i * 16 + tk;
    f32x4 v = *(const f32x4*)(ib + (size_t)k * C + tc);
    tile[tc + 0][k] = (unsigned short)f2bf(v[0]);
    tile[tc + 1][k] = (unsigned short)f2bf(v[1]);
    tile[tc + 2][k] = (unsigned short)f2bf(v[2]);
    tile[tc + 3][k] = (unsigned short)f2bf(v[3]);
  }
  __syncthreads();
  int oc = t >> 2;
  int ok = (t & 3) * 16;
  unsigned short buf[16];
  #pragma unroll
  for (int j = 0; j < 16; ++j) buf[j] = tile[oc][ok + j];
  unsigned short* dst = ob + (size_t)oc * K + ok;
  *(bf16x8*)(dst) = *(const bf16x8*)(buf);
  *(bf16x8*)(dst + 8) = *(const bf16x8*)(buf + 8);
}

// ---------------- x -> bf16 prepass ----------------
__global__ __launch_bounds__(256) void cvtx_k(
    const float* __restrict__ x, unsigned short* __restrict__ xb)
{
  int i = (blockIdx.x * 256 + threadIdx.x) * 8;
  f32x4 a = *(const f32x4*)(x + i);
  f32x4 b = *(const f32x4*)(x + i + 4);
  u32x4 o;
  o[0] = pkbf(a[0], a[1]); o[1] = pkbf(a[2], a[3]);
  o[2] = pkbf(b[0], b[1]); o[3] = pkbf(b[2], b[3]);
  *(u32x4*)(xb + i) = o;
}

// ---------------- router: fp64 logits, top-2 ----------------
__global__ __launch_bounds__(64) void router_k(
    const float* __restrict__ x, const float* __restrict__ gw,
    float* __restrict__ logits, int* __restrict__ cnt,
    int* __restrict__ tok_e, int* __restrict__ tok_r, float* __restrict__ tok_w)
{
  int t = blockIdx.x, l = threadIdx.x;
  const float* xr = x + (size_t)t * H;
  double acc[NE];
  #pragma unroll
  for (int e = 0; e < NE; ++e) acc[e] = 0.0;
  for (int j = 0; j < H / 64; ++j) {
    int h = j * 64 + l;
    float xv = xr[h];
    #pragma unroll
    for (int e = 0; e < NE; ++e) acc[e] += (double)xv * (double)gw[e * H + h];
  }
  #pragma unroll
  for (int off = 32; off >= 1; off >>= 1) {
    #pragma unroll
    for (int e = 0; e < NE; ++e) acc[e] += __shfl_down(acc[e], off, 64);
  }
  if (l == 0) {
    float lg[NE];
    #pragma unroll
    for (int e = 0; e < NE; ++e) { lg[e] = (float)acc[e]; logits[t * NE + e] = lg[e]; }
    int i0 = 0;
    for (int e = 1; e < NE; ++e) if (lg[e] > lg[i0]) i0 = e;
    int i1 = (i0 == 0) ? 1 : 0;
    for (int e = 0; e < NE; ++e) if (e != i0 && lg[e] > lg[i1]) i1 = e;
    float w0 = 1.f / (1.f + expf(lg[i1] - lg[i0]));
    float w1 = 1.f / (1.f + expf(lg[i0] - lg[i1]));
    int r0 = atomicAdd(&cnt[i0], 1);
    int r1 = atomicAdd(&cnt[i1], 1);
    tok_e[2 * t] = i0;     tok_r[2 * t] = r0;     tok_w[2 * t] = w0;
    tok_e[2 * t + 1] = i1; tok_r[2 * t + 1] = r1; tok_w[2 * t + 1] = w1;
  }
}

// ---------------- scan + gather list ----------------
__global__ __launch_bounds__(1024) void build_k(
    const int* __restrict__ cnt, int* __restrict__ base,
    const int* __restrict__ tok_e, const int* __restrict__ tok_r,
    const float* __restrict__ tok_w, int* __restrict__ gtok, float* __restrict__ gws)
{
  __shared__ int sb[NE];
  if (threadIdx.x == 0) {
    int s = 0;
    for (int e = 0; e < NE; ++e) { sb[e] = s; base[e] = s; s += cnt[e]; }
  }
  __syncthreads();
  int t = threadIdx.x;
  #pragma unroll
  for (int k = 0; k < 2; ++k) {
    int e = tok_e[2 * t + k];
    int slot = sb[e] + tok_r[2 * t + k];
    gtok[slot] = t;
    gws[slot] = tok_w[2 * t + k];
  }
}

// ---------------- ffn1: fragment-direct register GEMM, M=64, N=256 (128g+128u) ----------------
// All operands bf16 k-contiguous: every fragment = one b128 global load. No LDS/barriers.
__global__ __launch_bounds__(256, 4) void ffn1_k(
    const unsigned short* __restrict__ xb, const unsigned short* __restrict__ wt1,
    const int* __restrict__ cnt, const int* __restrict__ base,
    const int* __restrict__ gtok, unsigned short* __restrict__ act)
{
  // 3584 blocks = 8 XCD * 448 (one expert per XCD); per XCD: 28 p * 16 mB, mB fastest
  int wg = (blockIdx.x & 7) * 448 + (blockIdx.x >> 3);
  int mB = wg & 15;
  int rest = wg >> 4;                 // 0..223
  int e = rest / 28, p = rest % 28;
  int n = cnt[e];
  int m0 = mB * 64;
  if (m0 >= n) return;
  int sb = base[e];
  int tid = threadIdx.x;
  int wv = tid >> 6, lane = tid & 63, lr = lane & 15, lg = lane >> 4;

  // B fragment pointers: wt1[e][col][k]; cols: gate p*128+wv*32+{0,16}+lr, up +F
  const unsigned short* bp[4];
  #pragma unroll
  for (int cf = 0; cf < 4; ++cf) {
    int col = p * 128 + wv * 32 + (cf & 1) * 16 + lr + ((cf >> 1) ? F : 0);
    bp[cf] = wt1 + (size_t)(e * F2 + col) * H + lg * 8;
  }
  // A fragment pointers (token gather, clamped)
  const unsigned short* ax[4];
  #pragma unroll
  for (int mf = 0; mf < 4; ++mf) {
    int sl = m0 + mf * 16 + lr; if (sl >= n) sl = n - 1;
    ax[mf] = xb + (size_t)gtok[sb + sl] * H + lg * 8;
  }

  f32x4 acc[4][4];
  #pragma unroll
  for (int mf = 0; mf < 4; ++mf)
    #pragma unroll
    for (int cf = 0; cf < 4; ++cf) acc[mf][cf] = (f32x4)0.f;

  for (int s = 0; s < 32; ++s) {
    bf16x8 b0 = *(const bf16x8*)(bp[0] + s * 32);
    bf16x8 b1 = *(const bf16x8*)(bp[1] + s * 32);
    bf16x8 b2 = *(const bf16x8*)(bp[2] + s * 32);
    bf16x8 b3 = *(const bf16x8*)(bp[3] + s * 32);
    #pragma unroll
    for (int mf = 0; mf < 4; ++mf) {
      bf16x8 af = *(const bf16x8*)(ax[mf] + s * 32);
      acc[mf][0] = MFMA16(af, b0, acc[mf][0]);
      acc[mf][1] = MFMA16(af, b1, acc[mf][1]);
      acc[mf][2] = MFMA16(af, b2, acc[mf][2]);
      acc[mf][3] = MFMA16(af, b3, acc[mf][3]);
    }
  }

  // epilogue: silu(gate)*up; gate cf 0..1, up cf 2..3
  #pragma unroll
  for (int mf = 0; mf < 4; ++mf) {
    #pragma unroll
    for (int g = 0; g < 2; ++g) {
      int fcol = p * 128 + wv * 32 + g * 16 + lr;
      #pragma unroll
      for (int r = 0; r < 4; ++r) {
        int sl = m0 + mf * 16 + lg * 4 + r;
        if (sl < n) {
          float gg = acc[mf][g][r], u = acc[mf][g + 2][r];
          act[(size_t)(sb + sl) * F + fcol] = (unsigned short)f2bf(gg / (1.f + expf(-gg)) * u);
        }
      }
    }
  }
}

// ---------------- ffn2: fragment-direct register GEMM, M=64, N=128, K-split x4 ----------------
__global__ __launch_bounds__(256, 4) void ffn2_k(
    const unsigned short* __restrict__ act, const unsigned short* __restrict__ wt2,
    const int* __restrict__ cnt, const int* __restrict__ base,
    const int* __restrict__ gtok, const float* __restrict__ gws,
    float* __restrict__ out)
{
  // 4096 blocks = 8 XCD * 512 (one expert per XCD): 16 mB * 8 p * 4 kh, mB fastest
  int wg = (blockIdx.x & 7) * 512 + (blockIdx.x >> 3);
  int mB = wg & 15;
  int rest = wg >> 4;                // 0..255
  int p = rest & 7;
  int kh = (rest >> 3) & 3;
  int e = rest >> 5;
  int n = cnt[e];
  int m0 = mB * 64;
  if (m0 >= n) return;
  int sb = base[e];
  int tid = threadIdx.x;
  int wv = tid >> 6, lane = tid & 63, lr = lane & 15, lg = lane >> 4;
  const int kbase = kh * 896;

  // B fragment pointers: wt2[e][hcol][f]
  const unsigned short* bp[2];
  #pragma unroll
  for (int cf = 0; cf < 2; ++cf) {
    int col = p * 128 + wv * 32 + cf * 16 + lr;
    bp[cf] = wt2 + (size_t)(e * H + col) * F + kbase + lg * 8;
  }
  const unsigned short* ax[4];
  #pragma unroll
  for (int mf = 0; mf < 4; ++mf) {
    int sl = m0 + mf * 16 + lr; if (sl >= n) sl = n - 1;
    ax[mf] = act + (size_t)(sb + sl) * F + kbase + lg * 8;
  }

  f32x4 acc[4][2];
  #pragma unroll
  for (int mf = 0; mf < 4; ++mf) { acc[mf][0] = (f32x4)0.f; acc[mf][1] = (f32x4)0.f; }

  for (int s = 0; s < 28; ++s) {
    bf16x8 b0 = *(const bf16x8*)(bp[0] + s * 32);
    bf16x8 b1 = *(const bf16x8*)(bp[1] + s * 32);
    #pragma unroll
    for (int mf = 0; mf < 4; ++mf) {
      bf16x8 af = *(const bf16x8*)(ax[mf] + s * 32);
      acc[mf][0] = MFMA16(af, b0, acc[mf][0]);
      acc[mf][1] = MFMA16(af, b1, acc[mf][1]);
    }
  }

  #pragma unroll
  for (int mf = 0; mf < 4; ++mf) {
    #pragma unroll
    for (int cf = 0; cf < 2; ++cf) {
      int col = p * 128 + wv * 32 + cf * 16 + lr;
      #pragma unroll
      for (int r = 0; r < 4; ++r) {
        int sl = m0 + mf * 16 + lg * 4 + r;
        if (sl < n) {
          int slot = sb + sl;
          atomicAdd(&out[(size_t)gtok[slot] * H + col], gws[slot] * acc[mf][cf][r]);
        }
      }
    }
  }
}

extern "C" void kernel_launch(void* const* d_in, const int* in_sizes, int n_in,
                              void* d_out, int out_size, void* d_ws, size_t ws_size,
                              hipStream_t stream)
{
  const float* x   = (const float*)d_in[0];
  const float* gw  = (const float*)d_in[1];
  const float* wgu = (const float*)d_in[2];
  const float* wdn = (const float*)d_in[3];
  float* out = (float*)d_out;
  float* logits = out + (size_t)T * H;

  char* w = (char*)d_ws;
  int*   cnt = (int*)(w);
  int*   bs  = (int*)(w + 32);
  int*   te  = (int*)(w + 64);
  int*   tr  = (int*)(w + 64 + 8192);
  float* tw  = (float*)(w + 64 + 16384);
  int*   gt  = (int*)(w + 64 + 24576);
  float* gwt = (float*)(w + 64 + 32768);
  unsigned short* act = (unsigned short*)(w + 65536);      // 2048x3584 bf16 = 14.68 MB
  unsigned short* xb  = (unsigned short*)(w + 14745600);   // 1024x1024 bf16 = 2 MB
  unsigned short* wt1 = (unsigned short*)(w + 16842752);   // 8x7168x1024 bf16 = 117.4 MB
  unsigned short* wt2 = (unsigned short*)(w + 134283264);  // 8x1024x3584 bf16 = 58.7 MB
  // total ws need ~193 MB

  hipMemsetAsync(d_out, 0, (size_t)T * H * sizeof(float), stream);
  hipMemsetAsync(cnt, 0, NE * sizeof(int), stream);
  tr_k<<<dim3(F2 / 64, H / 64, NE), 256, 0, stream>>>(wgu, wt1, H, F2);
  tr_k<<<dim3(H / 64, F / 64, NE), 256, 0, stream>>>(wdn, wt2, F, H);
  cvtx_k<<<512, 256, 0, stream>>>(x, xb);
  router_k<<<T, 64, 0, stream>>>(x, gw, logits, cnt, te, tr, tw);
  build_k<<<1, 1024, 0, stream>>>(cnt, bs, te, tr, tw, gt, gwt);
  ffn1_k<<<3584, 256, 0, stream>>>(xb, wt1, cnt, bs, gt, act);
  ffn2_k<<<4096, 256, 0, stream>>>(act, wt2, cnt, bs, gt, gwt, out);
}